// Round 9
// baseline (48.013 us; speedup 1.0000x reference)
//
#include <hip/hip_runtime.h>
#include <stdint.h>

#define BB 4
#define NN 2048
#define F_IN 128
#define F_OUT 256
#define NH 4
#define HD 64

typedef float f32x4 __attribute__((ext_vector_type(4)));
typedef float f32x2 __attribute__((ext_vector_type(2)));
typedef short s16x8 __attribute__((ext_vector_type(8)));
typedef int i32x4 __attribute__((ext_vector_type(4)));
typedef unsigned long long u64;
typedef unsigned short u16;

#define LOG2E 1.4426950408889634f

__device__ __forceinline__ u16 f32_to_bf16_rtn(float f) {
    union { float f; uint32_t u; } v; v.f = f;
    uint32_t u = v.u;
    u += 0x7fffu + ((u >> 16) & 1u);
    return (u16)(u >> 16);
}

__device__ __forceinline__ float exp2_fast(float x) {
#if __has_builtin(__builtin_amdgcn_exp2f)
    return __builtin_amdgcn_exp2f(x);
#else
    return exp2f(x);
#endif
}

__device__ __forceinline__ int sbfe1(uint32_t v, int k) {
#if __has_builtin(__builtin_amdgcn_sbfe)
    return __builtin_amdgcn_sbfe((int)v, k, 1);   // bit k sign-extended: 0 or -1
#else
    return ((int32_t)(v << (31 - k))) >> 31;
#endif
}

// K01: fused adj-pack (HBM-streaming) + projection (VALU/LDS).
// Blocks 0..511 = proj (16-row tiles); 512..2559 = pack.
// Proj emits: hB (B-fragment bf16 layout), el' (log2e-scaled), and the
// factored-softmax tables er12[j] = {2^er', 2^(0.2 er')} (float2).
__global__ __launch_bounds__(256) void k01(
    const int* __restrict__ adj, const float* __restrict__ x,
    const float* __restrict__ W, const float* __restrict__ a_l,
    const float* __restrict__ a_r, u64* __restrict__ abits,
    u16* __restrict__ hB, float* __restrict__ el, f32x2* __restrict__ er12)
{
    const int t = threadIdx.x;

    __shared__ __align__(16) float xs[16][F_IN];      // 8 KB
    __shared__ __align__(16) float redl[4 * 64 * 20]; // 20 KB
    __shared__ __align__(16) float redr[4 * 64 * 20]; // 20 KB

    if (blockIdx.x >= 512) {
        // ---- pack adj int32 -> bitmask u64[B*N][32], one wave per row ----
        const int wid = ((blockIdx.x - 512) << 2) | (t >> 6);
        const int lane = t & 63;
        const int* rowp = adj + (size_t)wid * NN;
        u64 mym = 0;
#pragma unroll 8
        for (int jt = 0; jt < 32; ++jt) {
            int v = rowp[jt * 64 + lane];
            u64 m = __ballot(v != 0);
            if (lane == jt) mym = m;
        }
        if (lane < 32) abits[(size_t)wid * 32 + lane] = mym;
        return;
    }

    // ---- projection: h = x @ W^T (fp32) ----
    const int b = blockIdx.x >> 7;
    const int n0 = (blockIdx.x & 127) * 16;

    {
        const f32x4* src = (const f32x4*)(x + ((size_t)b * NN + n0) * F_IN);
        f32x4* dst = (f32x4*)&xs[0][0];
        dst[t] = src[t];
        dst[t + 256] = src[t + 256];
    }
    __syncthreads();

    float acc[16];
#pragma unroll
    for (int n = 0; n < 16; ++n) acc[n] = 0.f;

    const float* wrow = W + (size_t)t * F_IN;
#pragma unroll 2
    for (int k0 = 0; k0 < F_IN; k0 += 8) {
        f32x4 w0 = *(const f32x4*)(wrow + k0);
        f32x4 w1 = *(const f32x4*)(wrow + k0 + 4);
#pragma unroll
        for (int n = 0; n < 16; ++n) {
            f32x4 xa = *(const f32x4*)&xs[n][k0];
            f32x4 xb = *(const f32x4*)&xs[n][k0 + 4];
            float s = acc[n];
            s = fmaf(xa[0], w0[0], s); s = fmaf(xa[1], w0[1], s);
            s = fmaf(xa[2], w0[2], s); s = fmaf(xa[3], w0[3], s);
            s = fmaf(xb[0], w1[0], s); s = fmaf(xb[1], w1[1], s);
            s = fmaf(xb[2], w1[2], s); s = fmaf(xb[3], w1[3], s);
            acc[n] = s;
        }
    }

    // e_l / e_r via LDS transpose reduce.
    const int w = t >> 6, lane = t & 63;
    const float al = a_l[t];
    const float ar = a_r[t];
    {
        float* rl = &redl[((size_t)w * 64 + lane) * 20];
        float* rr = &redr[((size_t)w * 64 + lane) * 20];
#pragma unroll
        for (int q = 0; q < 4; ++q) {
            f32x4 vl, vr;
#pragma unroll
            for (int e = 0; e < 4; ++e) {
                vl[e] = acc[q * 4 + e] * al;
                vr[e] = acc[q * 4 + e] * ar;
            }
            *(f32x4*)(rl + q * 4) = vl;
            *(f32x4*)(rr + q * 4) = vr;
        }
    }
    __syncthreads();
    {
        const int n_ = lane & 15, og = lane >> 4;
        float sl = 0.f, sr = 0.f;
#pragma unroll
        for (int oo = 0; oo < 16; ++oo) {
            const int o = og + 4 * oo;
            sl += redl[((size_t)w * 64 + o) * 20 + n_];
            sr += redr[((size_t)w * 64 + o) * 20 + n_];
        }
        sl += __shfl_xor(sl, 16, 64); sl += __shfl_xor(sl, 32, 64);
        sr += __shfl_xor(sr, 16, 64); sr += __shfl_xor(sr, 32, 64);
        if (lane < 16) {
            el[((size_t)b * NH + w) * NN + n0 + lane] = sl * LOG2E;
            float sre = sr * LOG2E;
            f32x2 v2; v2[0] = exp2_fast(sre); v2[1] = exp2_fast(0.2f * sre);
            er12[((size_t)b * NH + w) * NN + n0 + lane] = v2;
        }
    }

    // B-fragment layout store: hB[b][jt32][head][cb][lane64][8] (bf16)
    const int dcol = t & 15, cb = (t >> 4) & 3;
    const int jt32 = n0 >> 5;
    const int lb = dcol + ((n0 >> 3) & 2) * 16;
    u16* hb = hB + ((((size_t)b * 64 + jt32) * 4 + w) * 4 + cb) * 512 + (size_t)lb * 8;
    s16x8 pk0, pk1;
#pragma unroll
    for (int n = 0; n < 8; ++n) pk0[n] = (short)f32_to_bf16_rtn(acc[n]);
#pragma unroll
    for (int n = 0; n < 8; ++n) pk1[n] = (short)f32_to_bf16_rtn(acc[n + 8]);
    *(s16x8*)hb         = pk0;
    *(s16x8*)(hb + 128) = pk1;
}

// K2: fused masked softmax + aggregation, exp-free inner loop:
// p = (t>=1) ? t : E2i*E2j with t = E1i*E1j (factored leaky-relu softmax).
// wave = (b, head, 32-row i-tile, j-quarter); dist-1 register prefetch of
// B-frags + er12; masks dwordx4 per 4-iter group. Cross-jq LDS reduce at end.
__global__ __launch_bounds__(256, 3) void k2_attn(
    const uint32_t* __restrict__ abits32, const u16* __restrict__ hB,
    const float* __restrict__ el, const f32x2* __restrict__ er12,
    float* __restrict__ out)
{
    const int t = threadIdx.x;
    const int jq = t >> 6, l = t & 63;
    int bid = blockIdx.x;
    bid = (bid & 7) * 128 + (bid >> 3);   // XCD swizzle (1024 % 8 == 0, bijective)
    const int b = bid >> 8;
    const int w = (bid >> 6) & 3;         // head
    const int i0 = (bid & 63) * 32;
    const int r = l & 15;                 // A row / D col
    const int kb = l >> 4;                // k-slice 0..3
    const int ks = kb * 8;
    const int irow0 = i0 + r, irow1 = irow0 + 16;

    const u16* hbp = hB + ((((size_t)b * 64 + jq * 16) * 4 + w) * 4) * 512 + (size_t)l * 8;
    const f32x2* erp = er12 + ((size_t)b * NH + w) * NN + jq * 512 + ks;
    const i32x4* m0p4 = (const i32x4*)(abits32 + ((size_t)b * NN + irow0) * 64 + jq * 16);
    const i32x4* m1p4 = (const i32x4*)(abits32 + ((size_t)b * NN + irow1) * 64 + jq * 16);

    const float eli0 = el[((size_t)b * NH + w) * NN + irow0];
    const float eli1 = el[((size_t)b * NH + w) * NN + irow1];
    const float E1i0 = exp2_fast(eli0), E2i0 = exp2_fast(0.2f * eli0);
    const float E1i1 = exp2_fast(eli1), E2i1 = exp2_fast(0.2f * eli1);

    f32x4 a00 = {0.f,0.f,0.f,0.f}, a01 = a00, a02 = a00, a03 = a00, as0 = a00;
    f32x4 a10 = a00, a11 = a00, a12 = a00, a13 = a00, as1 = a00;
    s16x8 ones;
#pragma unroll
    for (int k = 0; k < 8; ++k) ones[k] = (short)0x3F80;   // bf16 1.0

    // prologue: group-0 masks + iter-0 B-frags + iter-0 er12
    i32x4 mg0c = m0p4[0], mg1c = m1p4[0];
    s16x8 b0c = *(const s16x8*)(hbp + 0 * 512);
    s16x8 b1c = *(const s16x8*)(hbp + 1 * 512);
    s16x8 b2c = *(const s16x8*)(hbp + 2 * 512);
    s16x8 b3c = *(const s16x8*)(hbp + 3 * 512);
    f32x4 v0c = *(const f32x4*)(erp);
    f32x4 v1c = *(const f32x4*)(erp + 2);
    f32x4 v2c = *(const f32x4*)(erp + 4);
    f32x4 v3c = *(const f32x4*)(erp + 6);
    __builtin_amdgcn_sched_barrier(0);

#define MFMA_BF16 __builtin_amdgcn_mfma_f32_16x16x32_bf16
#define BODY(IT, S, PF)                                                       \
    {                                                                         \
        s16x8 b0n, b1n, b2n, b3n;                                             \
        f32x4 v0n, v1n, v2n, v3n;                                             \
        if (PF) { /* dist-1 prefetch: B-frags + er12 */                       \
            const u16* hp_ = hbp + (size_t)((IT) + 1) * 8192;                 \
            b0n = *(const s16x8*)(hp_ + 0 * 512);                             \
            b1n = *(const s16x8*)(hp_ + 1 * 512);                             \
            b2n = *(const s16x8*)(hp_ + 2 * 512);                             \
            b3n = *(const s16x8*)(hp_ + 3 * 512);                             \
            const f32x2* ep_ = erp + ((IT) + 1) * 32;                         \
            v0n = *(const f32x4*)(ep_);                                       \
            v1n = *(const f32x4*)(ep_ + 2);                                   \
            v2n = *(const f32x4*)(ep_ + 4);                                   \
            v3n = *(const f32x4*)(ep_ + 6);                                   \
        }                                                                     \
        __builtin_amdgcn_sched_barrier(0);                                    \
        uint32_t w2a = ((uint32_t)mg0c[S]) >> ks;                             \
        uint32_t w2b = ((uint32_t)mg1c[S]) >> ks;                             \
        uint32_t pua[8], pub[8];                                              \
        _Pragma("unroll")                                                     \
        for (int k = 0; k < 8; ++k) {                                         \
            f32x4 vv = (k < 2) ? v0c : ((k < 4) ? v1c : ((k < 6) ? v2c : v3c)); \
            float ej1 = vv[(k & 1) * 2];                                      \
            float ej2 = vv[(k & 1) * 2 + 1];                                  \
            float t0 = E1i0 * ej1, m0 = E2i0 * ej2;                           \
            float t1 = E1i1 * ej1, m1 = E2i1 * ej2;                           \
            float p0 = (t0 >= 1.0f) ? t0 : m0;                                \
            float p1 = (t1 >= 1.0f) ? t1 : m1;                                \
            union { float f; uint32_t u; } c0, c1; c0.f = p0; c1.f = p1;      \
            pua[k] = c0.u & (uint32_t)sbfe1(w2a, k);                          \
            pub[k] = c1.u & (uint32_t)sbfe1(w2b, k);                          \
        }                                                                     \
        union { s16x8 v; uint32_t u[4]; } afa, afb;                           \
        afa.u[0] = __builtin_amdgcn_perm(pua[1], pua[0], 0x07060302);         \
        afa.u[1] = __builtin_amdgcn_perm(pua[3], pua[2], 0x07060302);         \
        afa.u[2] = __builtin_amdgcn_perm(pua[5], pua[4], 0x07060302);         \
        afa.u[3] = __builtin_amdgcn_perm(pua[7], pua[6], 0x07060302);         \
        afb.u[0] = __builtin_amdgcn_perm(pub[1], pub[0], 0x07060302);         \
        afb.u[1] = __builtin_amdgcn_perm(pub[3], pub[2], 0x07060302);         \
        afb.u[2] = __builtin_amdgcn_perm(pub[5], pub[4], 0x07060302);         \
        afb.u[3] = __builtin_amdgcn_perm(pub[7], pub[6], 0x07060302);         \
        a00 = MFMA_BF16(afa.v, b0c, a00, 0, 0, 0);                            \
        a01 = MFMA_BF16(afa.v, b1c, a01, 0, 0, 0);                            \
        a02 = MFMA_BF16(afa.v, b2c, a02, 0, 0, 0);                            \
        a03 = MFMA_BF16(afa.v, b3c, a03, 0, 0, 0);                            \
        as0 = MFMA_BF16(afa.v, ones, as0, 0, 0, 0);                           \
        a10 = MFMA_BF16(afb.v, b0c, a10, 0, 0, 0);                            \
        a11 = MFMA_BF16(afb.v, b1c, a11, 0, 0, 0);                            \
        a12 = MFMA_BF16(afb.v, b2c, a12, 0, 0, 0);                            \
        a13 = MFMA_BF16(afb.v, b3c, a13, 0, 0, 0);                            \
        as1 = MFMA_BF16(afb.v, ones, as1, 0, 0, 0);                           \
        if (PF) { b0c = b0n; b1c = b1n; b2c = b2n; b3c = b3n;                 \
                  v0c = v0n; v1c = v1n; v2c = v2n; v3c = v3n; }               \
    }

    // groups 0..2: prefetch next group's masks; dist-1 B + er12 inside bodies
    for (int g = 0; g < 3; ++g) {
        i32x4 mg0n = m0p4[g + 1];
        i32x4 mg1n = m1p4[g + 1];
        __builtin_amdgcn_sched_barrier(0);
#pragma unroll
        for (int s = 0; s < 4; ++s) {
            const int it = g * 4 + s;
            BODY(it, s, 1);
        }
        mg0c = mg0n; mg1c = mg1n;
    }
    // group 3: peeled, static prefetch guards
#pragma unroll
    for (int s = 0; s < 4; ++s) {
        const int it = 12 + s;
        if (s < 3) { BODY(it, s, 1); } else { BODY(it, s, 0); }
    }

    // ---- cross-jq reduce through LDS (end-of-kernel only) ----
    __shared__ __align__(16) float racc[3 * 64 * 44];   // 33 KB
    if (jq > 0) {
        float* p = &racc[((jq - 1) * 64 + l) * 44];
        *(f32x4*)(p +  0) = a00; *(f32x4*)(p +  4) = a01;
        *(f32x4*)(p +  8) = a02; *(f32x4*)(p + 12) = a03;
        *(f32x4*)(p + 16) = as0;
        *(f32x4*)(p + 20) = a10; *(f32x4*)(p + 24) = a11;
        *(f32x4*)(p + 28) = a12; *(f32x4*)(p + 32) = a13;
        *(f32x4*)(p + 36) = as1;
    }
    __syncthreads();
    if (jq == 0) {
#pragma unroll
        for (int s = 0; s < 3; ++s) {
            const float* p = &racc[(s * 64 + l) * 44];
            a00 += *(const f32x4*)(p +  0); a01 += *(const f32x4*)(p +  4);
            a02 += *(const f32x4*)(p +  8); a03 += *(const f32x4*)(p + 12);
            as0 += *(const f32x4*)(p + 16);
            a10 += *(const f32x4*)(p + 20); a11 += *(const f32x4*)(p + 24);
            a12 += *(const f32x4*)(p + 28); a13 += *(const f32x4*)(p + 32);
            as1 += *(const f32x4*)(p + 36);
        }

        float* op = out + ((size_t)b * NN + i0) * F_OUT + w * HD;
#pragma unroll
        for (int q = 0; q < 4; ++q) {
            const int row0 = kb * 4 + q;
            float inv0 = 1.0f / as0[q];
            op[(size_t)row0 * F_OUT +  0 + r] = a00[q] * inv0;
            op[(size_t)row0 * F_OUT + 16 + r] = a01[q] * inv0;
            op[(size_t)row0 * F_OUT + 32 + r] = a02[q] * inv0;
            op[(size_t)row0 * F_OUT + 48 + r] = a03[q] * inv0;
            const int row1 = 16 + kb * 4 + q;
            float inv1 = 1.0f / as1[q];
            op[(size_t)row1 * F_OUT +  0 + r] = a10[q] * inv1;
            op[(size_t)row1 * F_OUT + 16 + r] = a11[q] * inv1;
            op[(size_t)row1 * F_OUT + 32 + r] = a12[q] * inv1;
            op[(size_t)row1 * F_OUT + 48 + r] = a13[q] * inv1;
        }
    }
}

extern "C" void kernel_launch(void* const* d_in, const int* in_sizes, int n_in,
                              void* d_out, int out_size, void* d_ws, size_t ws_size,
                              hipStream_t stream) {
    const float* x   = (const float*)d_in[0];
    const int*   adj = (const int*)d_in[1];
    const float* W   = (const float*)d_in[2];
    const float* a_l = (const float*)d_in[3];
    const float* a_r = (const float*)d_in[4];
    float* out = (float*)d_out;

    char* ws = (char*)d_ws;
    u16*   hB    = (u16*)ws;                                   // 4 MB
    u64*   abits = (u64*)(ws + (size_t)BB * F_OUT * NN * 2);   // 2 MB
    float* el    = (float*)(ws + (size_t)BB * F_OUT * NN * 2 + (size_t)BB * NN * 32 * 8);
    f32x2* er12  = (f32x2*)(el + (size_t)BB * NH * NN);

    k01<<<512 + BB * NN / 4, 256, 0, stream>>>(adj, x, W, a_l, a_r, abits, hB, el, er12);
    k2_attn<<<BB * NH * (NN / 32), 256, 0, stream>>>((const uint32_t*)abits, hB, el, er12, out);
}